// Round 3
// baseline (176.744 us; speedup 1.0000x reference)
//
#include <hip/hip_runtime.h>
#include <math.h>

#define B  2
#define S  2048
#define D  1024
#define NH 16
#define HD 64
#define NROWS (B * S)   // 4096

#define AS1 __attribute__((address_space(1)))
#define AS3 __attribute__((address_space(3)))
#define GLD16(g, l) __builtin_amdgcn_global_load_lds((const AS1 void*)(g), (AS3 void*)(l), 16, 0, 0)

typedef __attribute__((ext_vector_type(8))) short short8;   // 8 bf16
typedef __attribute__((ext_vector_type(4))) float floatx4;

#define MFMA16(a, b, c) __builtin_amdgcn_mfma_f32_16x16x32_bf16((a), (b), (c), 0, 0, 0)

// raw v_exp_f32 (2^x); inputs bounded in this kernel -> no libm range fixup
__device__ inline float fexp2(float x) { return __builtin_amdgcn_exp2f(x); }

__device__ inline unsigned short f2bf(float f) {
    union { float f; unsigned int u; } v; v.f = f;
    unsigned int u = v.u;
    u += 0x7fffu + ((u >> 16) & 1);     // RNE
    return (unsigned short)(u >> 16);
}

// two f32 -> packed bf16x2 (round-half-up) in one v_perm_b32
__device__ inline unsigned int pack2bf(float a, float b) {
    unsigned int ua = __float_as_uint(a) + 0x8000u;
    unsigned int ub = __float_as_uint(b) + 0x8000u;
    return __builtin_amdgcn_perm(ub, ua, 0x07060302u);
}

// ---------------------------------------------------------------------------
// fp32 -> bf16 conversion for x + weights, and RoPE cos/sin table build.
// ---------------------------------------------------------------------------
__global__ __launch_bounds__(256) void cvt_kernel(
    const float* __restrict__ x,  const float* __restrict__ Wq,
    const float* __restrict__ Wk, const float* __restrict__ Wv,
    const float* __restrict__ Wo,
    unsigned short* __restrict__ xb,  unsigned short* __restrict__ wqb,
    unsigned short* __restrict__ wkb, unsigned short* __restrict__ wvb,
    unsigned short* __restrict__ wob, float2* __restrict__ tab)
{
    size_t idx = (size_t)blockIdx.x * 256 + threadIdx.x;
    if (idx >= (2u << 20)) {                     // RoPE table region
        int tt = (int)(idx - (2u << 20));        // 0..16383
        int j  = tt >> 9;                        // 0..31
        int s0 = (tt & 511) << 2;                // 0..2044
        float invf = fexp2(-(float)j * (13.287712379549449f / 32.0f));
        #pragma unroll
        for (int p = 0; p < 4; ++p) {
            float sn, cs;
            __sincosf((float)(s0 + p) * invf, &sn, &cs);
            tab[j * 2048 + s0 + p] = make_float2(cs, sn);
        }
        return;
    }
    const float* src; unsigned short* dst; size_t off;
    if (idx < (1u << 20)) { src = x; dst = xb; off = idx << 2; }
    else {
        size_t r = idx - (1u << 20);
        int w = (int)(r >> 18);
        off = (r & ((1u << 18) - 1)) << 2;
        src = (w == 0) ? Wq : (w == 1) ? Wk : (w == 2) ? Wv : Wo;
        dst = (w == 0) ? wqb : (w == 1) ? wkb : (w == 2) ? wvb : wob;
    }
    float4 f = *(const float4*)(src + off);
    ushort4 o;
    o.x = f2bf(f.x); o.y = f2bf(f.y); o.z = f2bf(f.z); o.w = f2bf(f.w);
    *(ushort4*)(dst + off) = o;
}

// ---------------------------------------------------------------------------
// QKV GEMM, deep-pipelined 256x256 tile, BK=64, 8 waves (2M x 4N), 128 KB
// double-buffered LDS. Counted vmcnt(8): tile t+1's 8 global_load_lds stay
// in flight across the barriers while tile t computes (never vmcnt(0) in
// the main loop). LDS XOR-swizzle (chunk ^= row&7) applied on the READ side
// and inverse-applied on the GLOBAL SOURCE address (global_load_lds writes
// linearly - both-sides-or-neither). 2 barriers + 1 vmcnt per 64-K tile.
// Grid (16, 12) = 192 blocks, 1 block/CU.
// ---------------------------------------------------------------------------
#define SWAIT(n) asm volatile("s_waitcnt vmcnt(" n ")" ::: "memory")

#define STAGE8(p, kk)                                                          \
{                                                                              \
    _Pragma("unroll")                                                          \
    for (int hh = 0; hh < 2; ++hh) {                                           \
        _Pragma("unroll")                                                      \
        for (int jj = 0; jj < 2; ++jj) {                                       \
            const int idx = jj * 512 + t;                                      \
            const int row = hh * 128 + (idx >> 3);                             \
            const int ch  = (idx & 7) ^ (row & 7);                             \
            GLD16(Ab + (size_t)row * D + (kk) + ch * 8, &As[p][hh * 8192 + idx * 8]); \
            GLD16(Bb + (size_t)row * D + (kk) + ch * 8, &Bs[p][hh * 8192 + idx * 8]); \
        }                                                                      \
    }                                                                          \
}

#define QCOMP(p, ks)                                                           \
{                                                                              \
    short8 a[8], b[4];                                                         \
    _Pragma("unroll")                                                          \
    for (int mi = 0; mi < 8; ++mi)                                             \
        a[mi] = *(const short8*)&As[p][(wr * 128 + mi * 16 + lm) * 64 + (((ks) * 4 + quad) ^ sw) * 8]; \
    _Pragma("unroll")                                                          \
    for (int ni = 0; ni < 4; ++ni)                                             \
        b[ni] = *(const short8*)&Bs[p][(wc * 64 + ni * 16 + lm) * 64 + (((ks) * 4 + quad) ^ sw) * 8]; \
    __builtin_amdgcn_s_setprio(1);                                             \
    _Pragma("unroll")                                                          \
    for (int mi = 0; mi < 8; ++mi)                                             \
        _Pragma("unroll")                                                      \
        for (int ni = 0; ni < 4; ++ni)                                         \
            acc[mi][ni] = MFMA16(b[ni], a[mi], acc[mi][ni]);  /* SWAPPED */    \
    __builtin_amdgcn_s_setprio(0);                                             \
}

__global__ __launch_bounds__(512, 2) void gemm_qkv_mfma(
    const unsigned short* __restrict__ xb,
    const unsigned short* __restrict__ wqb,
    const unsigned short* __restrict__ wkb,
    const unsigned short* __restrict__ wvb,
    const float2* __restrict__ tab,
    unsigned short* __restrict__ Qo, unsigned short* __restrict__ Ko,
    unsigned short* __restrict__ Vo)   // Vo = Vt [bh][64][S]
{
    __shared__ short As[2][256 * 64];   // 32 KB each buf
    __shared__ short Bs[2][256 * 64];   // total 128 KB

    const int t    = threadIdx.x;
    const int wid  = t >> 6, lane = t & 63;
    const int lm   = lane & 15, quad = lane >> 4;
    const int wr   = wid >> 2, wc = wid & 3;     // 2M x 4N waves
    const int sw   = lm & 7;

    const int i0  = blockIdx.x * 256;
    const int by  = blockIdx.y;                  // 0..11
    const int mat = by >> 2;                     // 0=Q 1=K 2=V
    const int j0  = (by & 3) * 256;
    const unsigned short* __restrict__ W = (mat == 0) ? wqb : (mat == 1) ? wkb : wvb;
    unsigned short* __restrict__ out = (mat == 0) ? Qo : (mat == 1) ? Ko : Vo;

    const unsigned short* Ab = xb + (size_t)i0 * D;
    const unsigned short* Bb = W  + (size_t)j0 * D;

    floatx4 acc[8][4] = {};

    STAGE8(0, 0);                                // tile 0 -> buf 0
    for (int kt = 0; kt < 16; ++kt) {
        const int p = kt & 1;
        if (kt < 15) {
            STAGE8(p ^ 1, (kt + 1) * 64);        // tile t+1 -> other buf
            SWAIT("8");                          // drain tile t, keep t+1 flying
        } else {
            SWAIT("0");                          // final tile: full drain
        }
        __builtin_amdgcn_sched_barrier(0);
        __builtin_amdgcn_s_barrier();            // buf[p] visible to all waves
        __builtin_amdgcn_sched_barrier(0);
        QCOMP(p, 0);
        QCOMP(p, 1);
        __builtin_amdgcn_sched_barrier(0);
        __builtin_amdgcn_s_barrier();            // all reads of buf[p] done
    }

    const int h = (j0 >> 6) + wc;                // head, constant per wave
    if (mat < 2) {
        // Q/K: RoPE via table (lane-local pairs), ushort4 stores [bh][s][hd]
        #pragma unroll
        for (int mi = 0; mi < 8; ++mi) {
            const int mg = i0 + wr * 128 + mi * 16 + lm;
            const int si = mg & (S - 1), bb = mg >> 11;
            unsigned short* orow = out + ((size_t)(bb * NH + h) * S + si) * HD;
            #pragma unroll
            for (int ni = 0; ni < 4; ++ni) {
                const int dim0 = ni * 16 + quad * 4;     // 0..63 within head
                const int j = dim0 >> 1;
                float2 t0 = tab[j * 2048 + si];
                float2 t1 = tab[(j + 1) * 2048 + si];
                floatx4 v = acc[mi][ni];
                float r0 = v[0] * t0.x - v[1] * t0.y;
                float r1 = v[0] * t0.y + v[1] * t0.x;
                float r2 = v[2] * t1.x - v[3] * t1.y;
                float r3 = v[2] * t1.y + v[3] * t1.x;
                if (mat == 0) {                  // fold 1/(8*ln2) into Q
                    r0 *= 0.1803368801111204f; r1 *= 0.1803368801111204f;
                    r2 *= 0.1803368801111204f; r3 *= 0.1803368801111204f;
                }
                ushort4 pk;
                pk.x = f2bf(r0); pk.y = f2bf(r1);
                pk.z = f2bf(r2); pk.w = f2bf(r3);
                *(ushort4*)(orow + dim0) = pk;
            }
        }
    } else {
        // V: store transposed into Vt[bh][d][s] (fused vtrans)
        #pragma unroll
        for (int mi = 0; mi < 8; ++mi) {
            const int mg = i0 + wr * 128 + mi * 16 + lm;
            const int si = mg & (S - 1), bb = mg >> 11;
            unsigned short* vb = out + (size_t)(bb * NH + h) * HD * S + si;
            #pragma unroll
            for (int ni = 0; ni < 4; ++ni) {
                const int d0 = ni * 16 + quad * 4;
                #pragma unroll
                for (int p = 0; p < 4; ++p)
                    vb[(size_t)(d0 + p) * S] = f2bf(acc[mi][ni][p]);
            }
        }
    }
}

// ---------------------------------------------------------------------------
// out-proj GEMM (unchanged 64x128 structure): out = Cb @ Wo^T, fp32 output.
// ---------------------------------------------------------------------------
#define GSTAGE(Abase, Bbase, kk, AD, BD)                                       \
{                                                                              \
    GLD16(Abase + (size_t)rowA  * D + (kk) + koA,  AD + cA  * 8);              \
    GLD16(Bbase + (size_t)rowB0 * D + (kk) + koB0, BD + cB0 * 8);              \
    GLD16(Bbase + (size_t)rowB1 * D + (kk) + koB1, BD + cB1 * 8);              \
}

#define GCOMP(AC, BC)                                                          \
{                                                                              \
    short8 a[4], b[2];                                                         \
    _Pragma("unroll")                                                          \
    for (int mi = 0; mi < 4; ++mi)                                             \
        a[mi] = *(const short8*)&AC[(mi * 16 + lm) * 32 + quad * 8];           \
    _Pragma("unroll")                                                          \
    for (int ni = 0; ni < 2; ++ni)                                             \
        b[ni] = *(const short8*)&BC[(wave * 32 + ni * 16 + lm) * 32 + quad * 8]; \
    _Pragma("unroll")                                                          \
    for (int mi = 0; mi < 4; ++mi)                                             \
        _Pragma("unroll")                                                      \
        for (int ni = 0; ni < 2; ++ni)                                         \
            acc[mi][ni] = MFMA16(b[ni], a[mi], acc[mi][ni]);  /* SWAPPED */    \
}

#define GEMM_PREAMBLE                                                          \
    const int t    = threadIdx.x;                                              \
    const int wave = t >> 6, lane = t & 63;                                    \
    const int lm   = lane & 15, quad = lane >> 4;                              \
    const int cA   = wave * 64 + lane;                                         \
    const int rowA = cA >> 2,  koA  = (cA & 3) << 3;                           \
    const int cB0  = wave * 128 + lane;                                        \
    const int rowB0 = cB0 >> 2, koB0 = (cB0 & 3) << 3;                         \
    const int cB1  = cB0 + 64;                                                 \
    const int rowB1 = cB1 >> 2, koB1 = (cB1 & 3) << 3;

#define GEMM_KLOOP(Abase, Bbase)                                               \
    GSTAGE(Abase, Bbase, 0, As0, Bs0);                                         \
    __syncthreads();                                                           \
    for (int k0 = 0; k0 < D; k0 += 64) {                                       \
        GSTAGE(Abase, Bbase, k0 + 32, As1, Bs1);                               \
        GCOMP(As0, Bs0);                                                       \
        __syncthreads();                                                       \
        if (k0 + 64 < D) GSTAGE(Abase, Bbase, k0 + 64, As0, Bs0);              \
        GCOMP(As1, Bs1);                                                       \
        __syncthreads();                                                       \
    }

__global__ __launch_bounds__(256) void gemm_out_mfma(
    const unsigned short* __restrict__ Cb,
    const unsigned short* __restrict__ wob,
    float* __restrict__ out)
{
    __shared__ short As0[64 * 32];
    __shared__ short As1[64 * 32];
    __shared__ short Bs0[128 * 32];
    __shared__ short Bs1[128 * 32];

    GEMM_PREAMBLE
    const int i0 = blockIdx.x * 64;
    const int j0 = blockIdx.y * 128;

    const unsigned short* Abase = Cb  + (size_t)i0 * D;
    const unsigned short* Bbase = wob + (size_t)j0 * D;

    floatx4 acc[4][2] = {};
    GEMM_KLOOP(Abase, Bbase)

    #pragma unroll
    for (int mi = 0; mi < 4; ++mi) {
        const int mg = i0 + mi * 16 + lm;
        float* orow = out + (size_t)mg * D;
        #pragma unroll
        for (int ni = 0; ni < 2; ++ni) {
            const int ng = j0 + wave * 32 + ni * 16 + quad * 4;
            *(floatx4*)(orow + ng) = acc[mi][ni];
        }
    }
}

// ---------------------------------------------------------------------------
// MFMA flash attention, causal (R1 version restored). BM=64, 1024 blocks,
// 4 blocks/CU, single-barrier pipeline, no-max exp2 softmax,
// swapped QK^T -> packed Ps writes, scalar lsum.
// ---------------------------------------------------------------------------
#define ATTN_STEP(KC, VC, KN, VN)                                              \
{                                                                              \
    _Pragma("unroll")                                                          \
    for (int i = 0; i < 2; ++i) {                                              \
        int c = t + i * 256;                                                   \
        int row = c >> 3;                                                      \
        int dkc = (c & 7) ^ (row & 7);                                         \
        GLD16(Kg + (size_t)(k0n + row) * HD + dkc * 8, &KN[0][0] + c * 8);     \
        GLD16(Vg + (size_t)row * S + k0n + dkc * 8,    &VN[0][0] + c * 8);     \
    }                                                                          \
    short8 kb0[4], kb1[4];                                                     \
    _Pragma("unroll")                                                          \
    for (int nt = 0; nt < 4; ++nt) {                                           \
        kb0[nt] = *(const short8*)&KC[nt * 16 + lm][(quad ^ sw) * 8];          \
        kb1[nt] = *(const short8*)&KC[nt * 16 + lm][((4 + quad) ^ sw) * 8];    \
    }                                                                          \
    floatx4 sc[4];                                                             \
    _Pragma("unroll")                                                          \
    for (int nt = 0; nt < 4; ++nt) {                                           \
        floatx4 s = {0.f, 0.f, 0.f, 0.f};                                      \
        s = MFMA16(kb0[nt], qa0, s);   /* SWAPPED: row=k, col=q */             \
        s = MFMA16(kb1[nt], qa1, s);                                           \
        sc[nt] = s;                                                            \
    }                                                                          \
    if (diag) {                                                                \
        _Pragma("unroll")                                                      \
        for (int nt = 0; nt < 4; ++nt)                                         \
            _Pragma("unroll")                                                  \
            for (int r = 0; r < 4; ++r) {                                      \
                float pe = fexp2(sc[nt][r]);                                   \
                if (nt * 16 + quad * 4 + r > 16 * wave + lm) pe = 0.0f;        \
                sc[nt][r] = pe;                                                \
                lsum += pe;                                                    \
            }                                                                  \
    } else {                                                                   \
        _Pragma("unroll")                                                      \
        for (int nt = 0; nt < 4; ++nt)                                         \
            _Pragma("unroll")                                                  \
            for (int r = 0; r < 4; ++r) {                                      \
                float pe = fexp2(sc[nt][r]);                                   \
                sc[nt][r] = pe;                                                \
                lsum += pe;                                                    \
            }                                                                  \
    }                                                                          \
    _Pragma("unroll")                                                          \
    for (int nt = 0; nt < 4; ++nt) {                                           \
        uint2 pk;                                                              \
        pk.x = pack2bf(sc[nt][0], sc[nt][1]);                                  \
        pk.y = pack2bf(sc[nt][2], sc[nt][3]);                                  \
        int cp = (nt * 4 + quad) ^ psw;                                        \
        *(uint2*)&Ps[16 * wave + lm][cp * 4] = pk;                             \
    }                                                                          \
    short8 pa0 = *(const short8*)&Ps[16 * wave + lm][((quad * 2) ^ psw) * 4];  \
    short8 pa1 = *(const short8*)&Ps[16 * wave + lm][((8 + quad * 2) ^ psw) * 4]; \
    _Pragma("unroll")                                                          \
    for (int nt = 0; nt < 4; ++nt) {                                           \
        short8 vb0 = *(const short8*)&VC[nt * 16 + lm][(quad ^ sw) * 8];       \
        short8 vb1 = *(const short8*)&VC[nt * 16 + lm][((4 + quad) ^ sw) * 8]; \
        o[nt] = MFMA16(pa0, vb0, o[nt]);                                       \
        o[nt] = MFMA16(pa1, vb1, o[nt]);                                       \
    }                                                                          \
    __syncthreads();                                                           \
}

__global__ __launch_bounds__(256, 4) void attn_mfma(
    const unsigned short* __restrict__ Qb,   // [bh][s][64], pre-scaled 1/(8 ln2)
    const unsigned short* __restrict__ Kb,   // [bh][s][64]
    const unsigned short* __restrict__ Vt,   // [bh][64][S]
    unsigned short* __restrict__ Cb)         // [b][s][1024] bf16
{
    __shared__ unsigned short Ks0[64][64];
    __shared__ unsigned short Ks1[64][64];
    __shared__ unsigned short Vs0[64][64];
    __shared__ unsigned short Vs1[64][64];
    __shared__ unsigned short Ps[64][64];

    const int t    = threadIdx.x;
    const int lane = t & 63, wave = t >> 6;
    const int lm   = lane & 15, quad = lane >> 4;
    const int sw   = lm & 7;                 // 16B-chunk swizzle (K/V tiles)
    const int psw  = (lm & 7) << 1;          // 8B-chunk swizzle (Ps), even

    const int b     = blockIdx.x;
    const int bh    = b & 31;
    const int f     = (b >> 5) & 7;
    const int round = b >> 8;
    int qt;
    if      (round == 0) qt = f;
    else if (round == 1) qt = 15 - f;
    else if (round == 2) qt = 16 + f;
    else                 qt = 31 - f;
    const int q0 = qt * 64;

    const unsigned short* Qg = Qb + (size_t)bh * S * HD;
    const unsigned short* Kg = Kb + (size_t)bh * S * HD;
    const unsigned short* Vg = Vt + (size_t)bh * HD * S;

    short8 qa0 = *(const short8*)(Qg + (size_t)(q0 + 16 * wave + lm) * HD + quad * 8);
    short8 qa1 = *(const short8*)(Qg + (size_t)(q0 + 16 * wave + lm) * HD + 32 + quad * 8);

    #pragma unroll
    for (int i = 0; i < 2; ++i) {
        int c = t + i * 256;
        int row = c >> 3;
        int dkc = (c & 7) ^ (row & 7);
        GLD16(Kg + (size_t)row * HD + dkc * 8, &Ks0[0][0] + c * 8);
        GLD16(Vg + (size_t)row * S + dkc * 8,  &Vs0[0][0] + c * 8);
    }

    float lsum = 0.0f;
    floatx4 o[4] = {};

    __syncthreads();

    for (int kt = 0; kt <= qt; ++kt) {
        const int k0n = (kt + 1) * 64;
        const bool diag = (kt == qt);
        if ((kt & 1) == 0) ATTN_STEP(Ks0, Vs0, Ks1, Vs1)
        else               ATTN_STEP(Ks1, Vs1, Ks0, Vs0)
    }

    lsum += __shfl_xor(lsum, 16);
    lsum += __shfl_xor(lsum, 32);
    const int h = bh & (NH - 1), bb = bh >> 4;
    #pragma unroll
    for (int r = 0; r < 4; ++r) {
        float lr  = __shfl(lsum, (wave << 6 | (quad * 4 + r)) & 63);
        float inv = 1.0f / lr;
        size_t row = (size_t)bb * S + q0 + 16 * wave + quad * 4 + r;
        #pragma unroll
        for (int nt = 0; nt < 4; ++nt)
            Cb[row * D + h * HD + nt * 16 + lm] = f2bf(o[nt][r] * inv);
    }
}

extern "C" void kernel_launch(void* const* d_in, const int* in_sizes, int n_in,
                              void* d_out, int out_size, void* d_ws, size_t ws_size,
                              hipStream_t stream) {
    (void)in_sizes; (void)n_in; (void)out_size; (void)ws_size;
    const float* x  = (const float*)d_in[0];
    const float* Wq = (const float*)d_in[1];
    const float* Wk = (const float*)d_in[2];
    const float* Wv = (const float*)d_in[3];
    const float* Wo = (const float*)d_in[4];
    float* out = (float*)d_out;

    char* w = (char*)d_ws;
    unsigned short* Qb  = (unsigned short*)(w);                              // 8 MB
    unsigned short* Kb  = (unsigned short*)(w + (((size_t)8)  << 20));       // 8 MB
    unsigned short* Vtb = (unsigned short*)(w + (((size_t)16) << 20));       // 8 MB
    unsigned short* Cb  = (unsigned short*)(w + (((size_t)24) << 20));       // 8 MB
    unsigned short* xb  = (unsigned short*)(w + (((size_t)32) << 20));       // 8 MB
    unsigned short* wqb = (unsigned short*)(w + (((size_t)40) << 20));       // 2 MB
    unsigned short* wkb = (unsigned short*)(w + (((size_t)42) << 20));
    unsigned short* wvb = (unsigned short*)(w + (((size_t)44) << 20));
    unsigned short* wob = (unsigned short*)(w + (((size_t)46) << 20));
    float2*         tab = (float2*)(w + (((size_t)48) << 20));               // 512 KB

    cvt_kernel<<<8256, 256, 0, stream>>>(x, Wq, Wk, Wv, Wo,
                                         xb, wqb, wkb, wvb, wob, tab);

    dim3 g1(NROWS / 256, 12);
    gemm_qkv_mfma<<<g1, 512, 0, stream>>>(xb, wqb, wkb, wvb, tab, Qb, Kb, Vtb);

    attn_mfma<<<1024, 256, 0, stream>>>(Qb, Kb, Vtb, Cb);

    dim3 g3(NROWS / 64, D / 128);
    gemm_out_mfma<<<g3, 256, 0, stream>>>(Cb, wob, out);
}

// Round 4
// 169.083 us; speedup vs baseline: 1.0453x; 1.0453x over previous
//
#include <hip/hip_runtime.h>
#include <math.h>

#define B  2
#define S  2048
#define D  1024
#define NH 16
#define HD 64
#define NROWS (B * S)   // 4096

#define AS1 __attribute__((address_space(1)))
#define AS3 __attribute__((address_space(3)))
#define GLD16(g, l) __builtin_amdgcn_global_load_lds((const AS1 void*)(g), (AS3 void*)(l), 16, 0, 0)

typedef __attribute__((ext_vector_type(8))) short short8;   // 8 bf16
typedef __attribute__((ext_vector_type(4))) float floatx4;

#define MFMA16(a, b, c) __builtin_amdgcn_mfma_f32_16x16x32_bf16((a), (b), (c), 0, 0, 0)

// raw v_exp_f32 (2^x); inputs bounded in this kernel -> no libm range fixup
__device__ inline float fexp2(float x) { return __builtin_amdgcn_exp2f(x); }

__device__ inline unsigned short f2bf(float f) {
    union { float f; unsigned int u; } v; v.f = f;
    unsigned int u = v.u;
    u += 0x7fffu + ((u >> 16) & 1);     // RNE
    return (unsigned short)(u >> 16);
}

// two f32 -> packed bf16x2 (round-half-up) in one v_perm_b32
__device__ inline unsigned int pack2bf(float a, float b) {
    unsigned int ua = __float_as_uint(a) + 0x8000u;
    unsigned int ub = __float_as_uint(b) + 0x8000u;
    return __builtin_amdgcn_perm(ub, ua, 0x07060302u);
}

// ---------------------------------------------------------------------------
// fp32 -> bf16 conversion for x + weights, and RoPE cos/sin table build.
// Table layout [j][s] float2 (j = even-dim/2, 0..31; s = 0..2047).
// ---------------------------------------------------------------------------
__global__ __launch_bounds__(256) void cvt_kernel(
    const float* __restrict__ x,  const float* __restrict__ Wq,
    const float* __restrict__ Wk, const float* __restrict__ Wv,
    const float* __restrict__ Wo,
    unsigned short* __restrict__ xb,  unsigned short* __restrict__ wqb,
    unsigned short* __restrict__ wkb, unsigned short* __restrict__ wvb,
    unsigned short* __restrict__ wob, float2* __restrict__ tab)
{
    size_t idx = (size_t)blockIdx.x * 256 + threadIdx.x;
    if (idx >= (2u << 20)) {                     // RoPE table region
        int tt = (int)(idx - (2u << 20));        // 0..16383
        int j  = tt >> 9;                        // 0..31
        int s0 = (tt & 511) << 2;                // 0..2044
        float invf = fexp2(-(float)j * (13.287712379549449f / 32.0f));
        #pragma unroll
        for (int p = 0; p < 4; ++p) {
            float sn, cs;
            __sincosf((float)(s0 + p) * invf, &sn, &cs);
            tab[j * 2048 + s0 + p] = make_float2(cs, sn);
        }
        return;
    }
    const float* src; unsigned short* dst; size_t off;
    if (idx < (1u << 20)) { src = x; dst = xb; off = idx << 2; }
    else {
        size_t r = idx - (1u << 20);
        int w = (int)(r >> 18);
        off = (r & ((1u << 18) - 1)) << 2;
        src = (w == 0) ? Wq : (w == 1) ? Wk : (w == 2) ? Wv : Wo;
        dst = (w == 0) ? wqb : (w == 1) ? wkb : (w == 2) ? wvb : wob;
    }
    float4 f = *(const float4*)(src + off);
    ushort4 o;
    o.x = f2bf(f.x); o.y = f2bf(f.y); o.z = f2bf(f.z); o.w = f2bf(f.w);
    *(ushort4*)(dst + off) = o;
}

// ---------------------------------------------------------------------------
// QKV GEMM (R1 structure restored): 128x128 tile, BK=32 double-buffered,
// 4 waves in 2x2, 4x4 fragment acc. Grid (32,24)=768 blocks = 3/CU. 32 KB LDS.
// ---------------------------------------------------------------------------
#define G2STAGE(Abase, Bbase, kk, AD, BD)                                      \
{                                                                              \
    GLD16(Abase + (size_t)rowS        * D + (kk) + koS, AD + t * 8);           \
    GLD16(Abase + (size_t)(rowS + 64) * D + (kk) + koS, AD + 2048 + t * 8);    \
    GLD16(Bbase + (size_t)rowS        * D + (kk) + koS, BD + t * 8);           \
    GLD16(Bbase + (size_t)(rowS + 64) * D + (kk) + koS, BD + 2048 + t * 8);    \
}

#define G2COMP(AC, BC)                                                         \
{                                                                              \
    short8 a[4], b[4];                                                         \
    _Pragma("unroll")                                                          \
    for (int mi = 0; mi < 4; ++mi)                                             \
        a[mi] = *(const short8*)&AC[(wr * 64 + mi * 16 + lm) * 32 + quad * 8]; \
    _Pragma("unroll")                                                          \
    for (int ni = 0; ni < 4; ++ni)                                             \
        b[ni] = *(const short8*)&BC[(wc * 64 + ni * 16 + lm) * 32 + quad * 8]; \
    _Pragma("unroll")                                                          \
    for (int mi = 0; mi < 4; ++mi)                                             \
        _Pragma("unroll")                                                      \
        for (int ni = 0; ni < 4; ++ni)                                         \
            acc[mi][ni] = MFMA16(b[ni], a[mi], acc[mi][ni]);  /* SWAPPED */    \
}

__global__ __launch_bounds__(256, 3) void gemm_qkv_mfma(
    const unsigned short* __restrict__ xb,
    const unsigned short* __restrict__ wqb,
    const unsigned short* __restrict__ wkb,
    const unsigned short* __restrict__ wvb,
    const float2* __restrict__ tab,
    unsigned short* __restrict__ Qo, unsigned short* __restrict__ Ko,
    unsigned short* __restrict__ Vo)   // Vo = Vt [bh][64][S]
{
    __shared__ short As0[128 * 32];    // 8 KB each
    __shared__ short As1[128 * 32];
    __shared__ short Bs0[128 * 32];
    __shared__ short Bs1[128 * 32];    // total 32 KB

    const int t    = threadIdx.x;
    const int wave = t >> 6, lane = t & 63;
    const int lm   = lane & 15, quad = lane >> 4;
    const int wr   = wave >> 1, wc = wave & 1;
    const int rowS = t >> 2;
    const int koS  = (t & 3) << 3;

    const int i0  = blockIdx.x * 128;
    const int by  = blockIdx.y;                  // 0..23
    const int mat = by >> 3;                     // 0=Q 1=K 2=V
    const int j0  = (by & 7) * 128;
    const unsigned short* __restrict__ W = (mat == 0) ? wqb : (mat == 1) ? wkb : wvb;
    unsigned short* __restrict__ out = (mat == 0) ? Qo : (mat == 1) ? Ko : Vo;

    const unsigned short* Abase = xb + (size_t)i0 * D;
    const unsigned short* Bbase = W  + (size_t)j0 * D;

    floatx4 acc[4][4] = {};

    G2STAGE(Abase, Bbase, 0, As0, Bs0);
    __syncthreads();
    for (int k0 = 0; k0 < D; k0 += 64) {
        G2STAGE(Abase, Bbase, k0 + 32, As1, Bs1);
        G2COMP(As0, Bs0);
        __syncthreads();
        if (k0 + 64 < D) G2STAGE(Abase, Bbase, k0 + 64, As0, Bs0);
        G2COMP(As1, Bs1);
        __syncthreads();
    }

    const int h = (j0 + wc * 64) >> 6;           // head, constant per wave
    if (mat < 2) {
        // Q/K: RoPE via table (lane-local pairs), ushort4 stores [bh][s][hd]
        #pragma unroll
        for (int mi = 0; mi < 4; ++mi) {
            const int mg = i0 + wr * 64 + mi * 16 + lm;
            const int si = mg & (S - 1), bb = mg >> 11;
            unsigned short* orow = out + ((size_t)(bb * NH + h) * S + si) * HD;
            #pragma unroll
            for (int ni = 0; ni < 4; ++ni) {
                const int dim0 = ni * 16 + quad * 4;     // 0..63 within head
                const int j = dim0 >> 1;
                float2 t0 = tab[j * 2048 + si];
                float2 t1 = tab[(j + 1) * 2048 + si];
                floatx4 v = acc[mi][ni];
                float r0 = v[0] * t0.x - v[1] * t0.y;
                float r1 = v[0] * t0.y + v[1] * t0.x;
                float r2 = v[2] * t1.x - v[3] * t1.y;
                float r3 = v[2] * t1.y + v[3] * t1.x;
                if (mat == 0) {                  // fold 1/(8*ln2) into Q
                    r0 *= 0.1803368801111204f; r1 *= 0.1803368801111204f;
                    r2 *= 0.1803368801111204f; r3 *= 0.1803368801111204f;
                }
                ushort4 pk;
                pk.x = f2bf(r0); pk.y = f2bf(r1);
                pk.z = f2bf(r2); pk.w = f2bf(r3);
                *(ushort4*)(orow + dim0) = pk;
            }
        }
    } else {
        // V: store transposed into Vt[bh][d][s] (fused vtrans)
        #pragma unroll
        for (int mi = 0; mi < 4; ++mi) {
            const int mg = i0 + wr * 64 + mi * 16 + lm;
            const int si = mg & (S - 1), bb = mg >> 11;
            unsigned short* vb = out + (size_t)(bb * NH + h) * HD * S + si;
            #pragma unroll
            for (int ni = 0; ni < 4; ++ni) {
                const int d0 = ni * 16 + quad * 4;
                #pragma unroll
                for (int p = 0; p < 4; ++p)
                    vb[(size_t)(d0 + p) * S] = f2bf(acc[mi][ni][p]);
            }
        }
    }
}

// ---------------------------------------------------------------------------
// out-proj GEMM (unchanged 64x128 structure): out = Cb @ Wo^T, fp32 output.
// ---------------------------------------------------------------------------
#define GSTAGE(Abase, Bbase, kk, AD, BD)                                       \
{                                                                              \
    GLD16(Abase + (size_t)rowA  * D + (kk) + koA,  AD + cA  * 8);              \
    GLD16(Bbase + (size_t)rowB0 * D + (kk) + koB0, BD + cB0 * 8);              \
    GLD16(Bbase + (size_t)rowB1 * D + (kk) + koB1, BD + cB1 * 8);              \
}

#define GCOMP(AC, BC)                                                          \
{                                                                              \
    short8 a[4], b[2];                                                         \
    _Pragma("unroll")                                                          \
    for (int mi = 0; mi < 4; ++mi)                                             \
        a[mi] = *(const short8*)&AC[(mi * 16 + lm) * 32 + quad * 8];           \
    _Pragma("unroll")                                                          \
    for (int ni = 0; ni < 2; ++ni)                                             \
        b[ni] = *(const short8*)&BC[(wave * 32 + ni * 16 + lm) * 32 + quad * 8]; \
    _Pragma("unroll")                                                          \
    for (int mi = 0; mi < 4; ++mi)                                             \
        _Pragma("unroll")                                                      \
        for (int ni = 0; ni < 2; ++ni)                                         \
            acc[mi][ni] = MFMA16(b[ni], a[mi], acc[mi][ni]);  /* SWAPPED */    \
}

#define GEMM_PREAMBLE                                                          \
    const int t    = threadIdx.x;                                              \
    const int wave = t >> 6, lane = t & 63;                                    \
    const int lm   = lane & 15, quad = lane >> 4;                              \
    const int cA   = wave * 64 + lane;                                         \
    const int rowA = cA >> 2,  koA  = (cA & 3) << 3;                           \
    const int cB0  = wave * 128 + lane;                                        \
    const int rowB0 = cB0 >> 2, koB0 = (cB0 & 3) << 3;                         \
    const int cB1  = cB0 + 64;                                                 \
    const int rowB1 = cB1 >> 2, koB1 = (cB1 & 3) << 3;

#define GEMM_KLOOP(Abase, Bbase)                                               \
    GSTAGE(Abase, Bbase, 0, As0, Bs0);                                         \
    __syncthreads();                                                           \
    for (int k0 = 0; k0 < D; k0 += 64) {                                       \
        GSTAGE(Abase, Bbase, k0 + 32, As1, Bs1);                               \
        GCOMP(As0, Bs0);                                                       \
        __syncthreads();                                                       \
        if (k0 + 64 < D) GSTAGE(Abase, Bbase, k0 + 64, As0, Bs0);              \
        GCOMP(As1, Bs1);                                                       \
        __syncthreads();                                                       \
    }

__global__ __launch_bounds__(256) void gemm_out_mfma(
    const unsigned short* __restrict__ Cb,
    const unsigned short* __restrict__ wob,
    float* __restrict__ out)
{
    __shared__ short As0[64 * 32];
    __shared__ short As1[64 * 32];
    __shared__ short Bs0[128 * 32];
    __shared__ short Bs1[128 * 32];

    GEMM_PREAMBLE
    const int i0 = blockIdx.x * 64;
    const int j0 = blockIdx.y * 128;

    const unsigned short* Abase = Cb  + (size_t)i0 * D;
    const unsigned short* Bbase = wob + (size_t)j0 * D;

    floatx4 acc[4][2] = {};
    GEMM_KLOOP(Abase, Bbase)

    #pragma unroll
    for (int mi = 0; mi < 4; ++mi) {
        const int mg = i0 + mi * 16 + lm;
        float* orow = out + (size_t)mg * D;
        #pragma unroll
        for (int ni = 0; ni < 2; ++ni) {
            const int ng = j0 + wave * 32 + ni * 16 + quad * 4;
            *(floatx4*)(orow + ng) = acc[mi][ni];
        }
    }
}

// ---------------------------------------------------------------------------
// MFMA flash attention, causal. BM=64, 1024 blocks, 4 blocks/CU.
// NEW: softmax denominator computed on the MATRIX pipe - osum accumulates
// P·1 via two extra MFMAs per step (B-operand = bf16 ones), replacing 16
// scalar v_adds per step and the epilogue shuffle chain. Row layout of osum
// matches o exactly (same A-operand), so normalization is register-local.
// ---------------------------------------------------------------------------
#define ATTN_STEP(KC, VC, KN, VN)                                              \
{                                                                              \
    _Pragma("unroll")                                                          \
    for (int i = 0; i < 2; ++i) {                                              \
        int c = t + i * 256;                                                   \
        int row = c >> 3;                                                      \
        int dkc = (c & 7) ^ (row & 7);                                         \
        GLD16(Kg + (size_t)(k0n + row) * HD + dkc * 8, &KN[0][0] + c * 8);     \
        GLD16(Vg + (size_t)row * S + k0n + dkc * 8,    &VN[0][0] + c * 8);     \
    }                                                                          \
    short8 kb0[4], kb1[4];                                                     \
    _Pragma("unroll")                                                          \
    for (int nt = 0; nt < 4; ++nt) {                                           \
        kb0[nt] = *(const short8*)&KC[nt * 16 + lm][(quad ^ sw) * 8];          \
        kb1[nt] = *(const short8*)&KC[nt * 16 + lm][((4 + quad) ^ sw) * 8];    \
    }                                                                          \
    floatx4 sc[4];                                                             \
    _Pragma("unroll")                                                          \
    for (int nt = 0; nt < 4; ++nt) {                                           \
        floatx4 s = {0.f, 0.f, 0.f, 0.f};                                      \
        s = MFMA16(kb0[nt], qa0, s);   /* SWAPPED: row=k, col=q */             \
        s = MFMA16(kb1[nt], qa1, s);                                           \
        sc[nt] = s;                                                            \
    }                                                                          \
    if (diag) {                                                                \
        _Pragma("unroll")                                                      \
        for (int nt = 0; nt < 4; ++nt)                                         \
            _Pragma("unroll")                                                  \
            for (int r = 0; r < 4; ++r) {                                      \
                float pe = fexp2(sc[nt][r]);                                   \
                if (nt * 16 + quad * 4 + r > 16 * wave + lm) pe = 0.0f;        \
                sc[nt][r] = pe;                                                \
            }                                                                  \
    } else {                                                                   \
        _Pragma("unroll")                                                      \
        for (int nt = 0; nt < 4; ++nt)                                         \
            _Pragma("unroll")                                                  \
            for (int r = 0; r < 4; ++r)                                        \
                sc[nt][r] = fexp2(sc[nt][r]);                                  \
    }                                                                          \
    _Pragma("unroll")                                                          \
    for (int nt = 0; nt < 4; ++nt) {                                           \
        uint2 pk;                                                              \
        pk.x = pack2bf(sc[nt][0], sc[nt][1]);                                  \
        pk.y = pack2bf(sc[nt][2], sc[nt][3]);                                  \
        int cp = (nt * 4 + quad) ^ psw;                                        \
        *(uint2*)&Ps[16 * wave + lm][cp * 4] = pk;                             \
    }                                                                          \
    short8 pa0 = *(const short8*)&Ps[16 * wave + lm][((quad * 2) ^ psw) * 4];  \
    short8 pa1 = *(const short8*)&Ps[16 * wave + lm][((8 + quad * 2) ^ psw) * 4]; \
    osum = MFMA16(pa0, vones, osum);   /* row-sum of P via matrix pipe */      \
    osum = MFMA16(pa1, vones, osum);                                           \
    _Pragma("unroll")                                                          \
    for (int nt = 0; nt < 4; ++nt) {                                           \
        short8 vb0 = *(const short8*)&VC[nt * 16 + lm][(quad ^ sw) * 8];       \
        short8 vb1 = *(const short8*)&VC[nt * 16 + lm][((4 + quad) ^ sw) * 8]; \
        o[nt] = MFMA16(pa0, vb0, o[nt]);                                       \
        o[nt] = MFMA16(pa1, vb1, o[nt]);                                       \
    }                                                                          \
    __syncthreads();                                                           \
}

__global__ __launch_bounds__(256, 4) void attn_mfma(
    const unsigned short* __restrict__ Qb,   // [bh][s][64], pre-scaled 1/(8 ln2)
    const unsigned short* __restrict__ Kb,   // [bh][s][64]
    const unsigned short* __restrict__ Vt,   // [bh][64][S]
    unsigned short* __restrict__ Cb)         // [b][s][1024] bf16
{
    __shared__ unsigned short Ks0[64][64];
    __shared__ unsigned short Ks1[64][64];
    __shared__ unsigned short Vs0[64][64];
    __shared__ unsigned short Vs1[64][64];
    __shared__ unsigned short Ps[64][64];

    const int t    = threadIdx.x;
    const int lane = t & 63, wave = t >> 6;
    const int lm   = lane & 15, quad = lane >> 4;
    const int sw   = lm & 7;                 // 16B-chunk swizzle (K/V tiles)
    const int psw  = (lm & 7) << 1;          // 8B-chunk swizzle (Ps), even

    const int b     = blockIdx.x;
    const int bh    = b & 31;
    const int f     = (b >> 5) & 7;
    const int round = b >> 8;
    int qt;
    if      (round == 0) qt = f;
    else if (round == 1) qt = 15 - f;
    else if (round == 2) qt = 16 + f;
    else                 qt = 31 - f;
    const int q0 = qt * 64;

    const unsigned short* Qg = Qb + (size_t)bh * S * HD;
    const unsigned short* Kg = Kb + (size_t)bh * S * HD;
    const unsigned short* Vg = Vt + (size_t)bh * HD * S;

    short8 qa0 = *(const short8*)(Qg + (size_t)(q0 + 16 * wave + lm) * HD + quad * 8);
    short8 qa1 = *(const short8*)(Qg + (size_t)(q0 + 16 * wave + lm) * HD + 32 + quad * 8);

    short8 vones;
    #pragma unroll
    for (int i = 0; i < 8; ++i) vones[i] = (short)0x3F80;   // bf16 1.0

    #pragma unroll
    for (int i = 0; i < 2; ++i) {
        int c = t + i * 256;
        int row = c >> 3;
        int dkc = (c & 7) ^ (row & 7);
        GLD16(Kg + (size_t)row * HD + dkc * 8, &Ks0[0][0] + c * 8);
        GLD16(Vg + (size_t)row * S + dkc * 8,  &Vs0[0][0] + c * 8);
    }

    floatx4 o[4] = {};
    floatx4 osum = {};

    __syncthreads();

    for (int kt = 0; kt <= qt; ++kt) {
        const int k0n = (kt + 1) * 64;
        const bool diag = (kt == qt);
        if ((kt & 1) == 0) ATTN_STEP(Ks0, Vs0, Ks1, Vs1)
        else               ATTN_STEP(Ks1, Vs1, Ks0, Vs0)
    }

    const int h = bh & (NH - 1), bb = bh >> 4;
    #pragma unroll
    for (int r = 0; r < 4; ++r) {
        float inv = 1.0f / osum[r];
        size_t row = (size_t)bb * S + q0 + 16 * wave + quad * 4 + r;
        #pragma unroll
        for (int nt = 0; nt < 4; ++nt)
            Cb[row * D + h * HD + nt * 16 + lm] = f2bf(o[nt][r] * inv);
    }
}

extern "C" void kernel_launch(void* const* d_in, const int* in_sizes, int n_in,
                              void* d_out, int out_size, void* d_ws, size_t ws_size,
                              hipStream_t stream) {
    (void)in_sizes; (void)n_in; (void)out_size; (void)ws_size;
    const float* x  = (const float*)d_in[0];
    const float* Wq = (const float*)d_in[1];
    const float* Wk = (const float*)d_in[2];
    const float* Wv = (const float*)d_in[3];
    const float* Wo = (const float*)d_in[4];
    float* out = (float*)d_out;

    char* w = (char*)d_ws;
    unsigned short* Qb  = (unsigned short*)(w);                              // 8 MB
    unsigned short* Kb  = (unsigned short*)(w + (((size_t)8)  << 20));       // 8 MB
    unsigned short* Vtb = (unsigned short*)(w + (((size_t)16) << 20));       // 8 MB
    unsigned short* Cb  = (unsigned short*)(w + (((size_t)24) << 20));       // 8 MB
    unsigned short* xb  = (unsigned short*)(w + (((size_t)32) << 20));       // 8 MB
    unsigned short* wqb = (unsigned short*)(w + (((size_t)40) << 20));       // 2 MB
    unsigned short* wkb = (unsigned short*)(w + (((size_t)42) << 20));
    unsigned short* wvb = (unsigned short*)(w + (((size_t)44) << 20));
    unsigned short* wob = (unsigned short*)(w + (((size_t)46) << 20));
    float2*         tab = (float2*)(w + (((size_t)48) << 20));               // 512 KB

    cvt_kernel<<<8256, 256, 0, stream>>>(x, Wq, Wk, Wv, Wo,
                                         xb, wqb, wkb, wvb, wob, tab);

    dim3 g1(NROWS / 128, 24);
    gemm_qkv_mfma<<<g1, 256, 0, stream>>>(xb, wqb, wkb, wvb, tab, Qb, Kb, Vtb);

    attn_mfma<<<1024, 256, 0, stream>>>(Qb, Kb, Vtb, Cb);

    dim3 g3(NROWS / 64, D / 128);
    gemm_out_mfma<<<g3, 256, 0, stream>>>(Cb, wob, out);
}

// Round 5
// 167.967 us; speedup vs baseline: 1.0523x; 1.0066x over previous
//
#include <hip/hip_runtime.h>
#include <math.h>

#define B  2
#define S  2048
#define D  1024
#define NH 16
#define HD 64
#define NROWS (B * S)   // 4096

#define AS1 __attribute__((address_space(1)))
#define AS3 __attribute__((address_space(3)))
#define GLD16(g, l) __builtin_amdgcn_global_load_lds((const AS1 void*)(g), (AS3 void*)(l), 16, 0, 0)

typedef __attribute__((ext_vector_type(8))) short short8;   // 8 bf16
typedef __attribute__((ext_vector_type(4))) float floatx4;

#define MFMA16(a, b, c) __builtin_amdgcn_mfma_f32_16x16x32_bf16((a), (b), (c), 0, 0, 0)

// raw v_exp_f32 (2^x); inputs bounded in this kernel -> no libm range fixup
__device__ inline float fexp2(float x) { return __builtin_amdgcn_exp2f(x); }

__device__ inline unsigned short f2bf(float f) {
    union { float f; unsigned int u; } v; v.f = f;
    unsigned int u = v.u;
    u += 0x7fffu + ((u >> 16) & 1);     // RNE
    return (unsigned short)(u >> 16);
}

// two f32 -> packed bf16x2 (round-half-up) in one v_perm_b32
__device__ inline unsigned int pack2bf(float a, float b) {
    unsigned int ua = __float_as_uint(a) + 0x8000u;
    unsigned int ub = __float_as_uint(b) + 0x8000u;
    return __builtin_amdgcn_perm(ub, ua, 0x07060302u);
}

// ---------------------------------------------------------------------------
// fp32 -> bf16 conversion for x + weights, and RoPE cos/sin table build.
// Table layout [j][s] float2 (j = even-dim/2, 0..31; s = 0..2047).
// ---------------------------------------------------------------------------
__global__ __launch_bounds__(256) void cvt_kernel(
    const float* __restrict__ x,  const float* __restrict__ Wq,
    const float* __restrict__ Wk, const float* __restrict__ Wv,
    const float* __restrict__ Wo,
    unsigned short* __restrict__ xb,  unsigned short* __restrict__ wqb,
    unsigned short* __restrict__ wkb, unsigned short* __restrict__ wvb,
    unsigned short* __restrict__ wob, float2* __restrict__ tab)
{
    size_t idx = (size_t)blockIdx.x * 256 + threadIdx.x;
    if (idx >= (2u << 20)) {                     // RoPE table region
        int tt = (int)(idx - (2u << 20));        // 0..16383
        int j  = tt >> 9;                        // 0..31
        int s0 = (tt & 511) << 2;                // 0..2044
        float invf = fexp2(-(float)j * (13.287712379549449f / 32.0f));
        #pragma unroll
        for (int p = 0; p < 4; ++p) {
            float sn, cs;
            __sincosf((float)(s0 + p) * invf, &sn, &cs);
            tab[j * 2048 + s0 + p] = make_float2(cs, sn);
        }
        return;
    }
    const float* src; unsigned short* dst; size_t off;
    if (idx < (1u << 20)) { src = x; dst = xb; off = idx << 2; }
    else {
        size_t r = idx - (1u << 20);
        int w = (int)(r >> 18);
        off = (r & ((1u << 18) - 1)) << 2;
        src = (w == 0) ? Wq : (w == 1) ? Wk : (w == 2) ? Wv : Wo;
        dst = (w == 0) ? wqb : (w == 1) ? wkb : (w == 2) ? wvb : wob;
    }
    float4 f = *(const float4*)(src + off);
    ushort4 o;
    o.x = f2bf(f.x); o.y = f2bf(f.y); o.z = f2bf(f.z); o.w = f2bf(f.w);
    *(ushort4*)(dst + off) = o;
}

// ---------------------------------------------------------------------------
// QKV GEMM: 128x128 tile, BK=32 double-buffered, 4 waves in 2x2, 4x4
// fragment acc. Grid (32,24)=768 blocks = 3/CU. 32 KB LDS.
// ---------------------------------------------------------------------------
#define G2STAGE(Abase, Bbase, kk, AD, BD)                                      \
{                                                                              \
    GLD16(Abase + (size_t)rowS        * D + (kk) + koS, AD + t * 8);           \
    GLD16(Abase + (size_t)(rowS + 64) * D + (kk) + koS, AD + 2048 + t * 8);    \
    GLD16(Bbase + (size_t)rowS        * D + (kk) + koS, BD + t * 8);           \
    GLD16(Bbase + (size_t)(rowS + 64) * D + (kk) + koS, BD + 2048 + t * 8);    \
}

#define G2COMP(AC, BC)                                                         \
{                                                                              \
    short8 a[4], b[4];                                                         \
    _Pragma("unroll")                                                          \
    for (int mi = 0; mi < 4; ++mi)                                             \
        a[mi] = *(const short8*)&AC[(wr * 64 + mi * 16 + lm) * 32 + quad * 8]; \
    _Pragma("unroll")                                                          \
    for (int ni = 0; ni < 4; ++ni)                                             \
        b[ni] = *(const short8*)&BC[(wc * 64 + ni * 16 + lm) * 32 + quad * 8]; \
    _Pragma("unroll")                                                          \
    for (int mi = 0; mi < 4; ++mi)                                             \
        _Pragma("unroll")                                                      \
        for (int ni = 0; ni < 4; ++ni)                                         \
            acc[mi][ni] = MFMA16(b[ni], a[mi], acc[mi][ni]);  /* SWAPPED */    \
}

__global__ __launch_bounds__(256, 3) void gemm_qkv_mfma(
    const unsigned short* __restrict__ xb,
    const unsigned short* __restrict__ wqb,
    const unsigned short* __restrict__ wkb,
    const unsigned short* __restrict__ wvb,
    const float2* __restrict__ tab,
    unsigned short* __restrict__ Qo, unsigned short* __restrict__ Ko,
    unsigned short* __restrict__ Vo)   // Vo = Vt [bh][64][S]
{
    __shared__ short As0[128 * 32];    // 8 KB each
    __shared__ short As1[128 * 32];
    __shared__ short Bs0[128 * 32];
    __shared__ short Bs1[128 * 32];    // total 32 KB

    const int t    = threadIdx.x;
    const int wave = t >> 6, lane = t & 63;
    const int lm   = lane & 15, quad = lane >> 4;
    const int wr   = wave >> 1, wc = wave & 1;
    const int rowS = t >> 2;
    const int koS  = (t & 3) << 3;

    const int i0  = blockIdx.x * 128;
    const int by  = blockIdx.y;                  // 0..23
    const int mat = by >> 3;                     // 0=Q 1=K 2=V
    const int j0  = (by & 7) * 128;
    const unsigned short* __restrict__ W = (mat == 0) ? wqb : (mat == 1) ? wkb : wvb;
    unsigned short* __restrict__ out = (mat == 0) ? Qo : (mat == 1) ? Ko : Vo;

    const unsigned short* Abase = xb + (size_t)i0 * D;
    const unsigned short* Bbase = W  + (size_t)j0 * D;

    floatx4 acc[4][4] = {};

    G2STAGE(Abase, Bbase, 0, As0, Bs0);
    __syncthreads();
    for (int k0 = 0; k0 < D; k0 += 64) {
        G2STAGE(Abase, Bbase, k0 + 32, As1, Bs1);
        G2COMP(As0, Bs0);
        __syncthreads();
        if (k0 + 64 < D) G2STAGE(Abase, Bbase, k0 + 64, As0, Bs0);
        G2COMP(As1, Bs1);
        __syncthreads();
    }

    const int h = (j0 + wc * 64) >> 6;           // head, constant per wave
    if (mat < 2) {
        // Q/K: RoPE via table (lane-local pairs), ushort4 stores [bh][s][hd]
        #pragma unroll
        for (int mi = 0; mi < 4; ++mi) {
            const int mg = i0 + wr * 64 + mi * 16 + lm;
            const int si = mg & (S - 1), bb = mg >> 11;
            unsigned short* orow = out + ((size_t)(bb * NH + h) * S + si) * HD;
            #pragma unroll
            for (int ni = 0; ni < 4; ++ni) {
                const int dim0 = ni * 16 + quad * 4;     // 0..63 within head
                const int j = dim0 >> 1;
                float2 t0 = tab[j * 2048 + si];
                float2 t1 = tab[(j + 1) * 2048 + si];
                floatx4 v = acc[mi][ni];
                float r0 = v[0] * t0.x - v[1] * t0.y;
                float r1 = v[0] * t0.y + v[1] * t0.x;
                float r2 = v[2] * t1.x - v[3] * t1.y;
                float r3 = v[2] * t1.y + v[3] * t1.x;
                if (mat == 0) {                  // fold 1/(8*ln2) into Q
                    r0 *= 0.1803368801111204f; r1 *= 0.1803368801111204f;
                    r2 *= 0.1803368801111204f; r3 *= 0.1803368801111204f;
                }
                ushort4 pk;
                pk.x = f2bf(r0); pk.y = f2bf(r1);
                pk.z = f2bf(r2); pk.w = f2bf(r3);
                *(ushort4*)(orow + dim0) = pk;
            }
        }
    } else {
        // V: store transposed into Vt[bh][d][s] (fused vtrans)
        #pragma unroll
        for (int mi = 0; mi < 4; ++mi) {
            const int mg = i0 + wr * 64 + mi * 16 + lm;
            const int si = mg & (S - 1), bb = mg >> 11;
            unsigned short* vb = out + (size_t)(bb * NH + h) * HD * S + si;
            #pragma unroll
            for (int ni = 0; ni < 4; ++ni) {
                const int d0 = ni * 16 + quad * 4;
                #pragma unroll
                for (int p = 0; p < 4; ++p)
                    vb[(size_t)(d0 + p) * S] = f2bf(acc[mi][ni][p]);
            }
        }
    }
}

// ---------------------------------------------------------------------------
// out-proj GEMM (unchanged 64x128 structure): out = Cb @ Wo^T, fp32 output.
// ---------------------------------------------------------------------------
#define GSTAGE(Abase, Bbase, kk, AD, BD)                                       \
{                                                                              \
    GLD16(Abase + (size_t)rowA  * D + (kk) + koA,  AD + cA  * 8);              \
    GLD16(Bbase + (size_t)rowB0 * D + (kk) + koB0, BD + cB0 * 8);              \
    GLD16(Bbase + (size_t)rowB1 * D + (kk) + koB1, BD + cB1 * 8);              \
}

#define GCOMP(AC, BC)                                                          \
{                                                                              \
    short8 a[4], b[2];                                                         \
    _Pragma("unroll")                                                          \
    for (int mi = 0; mi < 4; ++mi)                                             \
        a[mi] = *(const short8*)&AC[(mi * 16 + lm) * 32 + quad * 8];           \
    _Pragma("unroll")                                                          \
    for (int ni = 0; ni < 2; ++ni)                                             \
        b[ni] = *(const short8*)&BC[(wave * 32 + ni * 16 + lm) * 32 + quad * 8]; \
    _Pragma("unroll")                                                          \
    for (int mi = 0; mi < 4; ++mi)                                             \
        _Pragma("unroll")                                                      \
        for (int ni = 0; ni < 2; ++ni)                                         \
            acc[mi][ni] = MFMA16(b[ni], a[mi], acc[mi][ni]);  /* SWAPPED */    \
}

#define GEMM_PREAMBLE                                                          \
    const int t    = threadIdx.x;                                              \
    const int wave = t >> 6, lane = t & 63;                                    \
    const int lm   = lane & 15, quad = lane >> 4;                              \
    const int cA   = wave * 64 + lane;                                         \
    const int rowA = cA >> 2,  koA  = (cA & 3) << 3;                           \
    const int cB0  = wave * 128 + lane;                                        \
    const int rowB0 = cB0 >> 2, koB0 = (cB0 & 3) << 3;                         \
    const int cB1  = cB0 + 64;                                                 \
    const int rowB1 = cB1 >> 2, koB1 = (cB1 & 3) << 3;

#define GEMM_KLOOP(Abase, Bbase)                                               \
    GSTAGE(Abase, Bbase, 0, As0, Bs0);                                         \
    __syncthreads();                                                           \
    for (int k0 = 0; k0 < D; k0 += 64) {                                       \
        GSTAGE(Abase, Bbase, k0 + 32, As1, Bs1);                               \
        GCOMP(As0, Bs0);                                                       \
        __syncthreads();                                                       \
        if (k0 + 64 < D) GSTAGE(Abase, Bbase, k0 + 64, As0, Bs0);              \
        GCOMP(As1, Bs1);                                                       \
        __syncthreads();                                                       \
    }

__global__ __launch_bounds__(256) void gemm_out_mfma(
    const unsigned short* __restrict__ Cb,
    const unsigned short* __restrict__ wob,
    float* __restrict__ out)
{
    __shared__ short As0[64 * 32];
    __shared__ short As1[64 * 32];
    __shared__ short Bs0[128 * 32];
    __shared__ short Bs1[128 * 32];

    GEMM_PREAMBLE
    const int i0 = blockIdx.x * 64;
    const int j0 = blockIdx.y * 128;

    const unsigned short* Abase = Cb  + (size_t)i0 * D;
    const unsigned short* Bbase = wob + (size_t)j0 * D;

    floatx4 acc[4][2] = {};
    GEMM_KLOOP(Abase, Bbase)

    #pragma unroll
    for (int mi = 0; mi < 4; ++mi) {
        const int mg = i0 + mi * 16 + lm;
        float* orow = out + (size_t)mg * D;
        #pragma unroll
        for (int ni = 0; ni < 2; ++ni) {
            const int ng = j0 + wave * 32 + ni * 16 + quad * 4;
            *(floatx4*)(orow + ng) = acc[mi][ni];
        }
    }
}

// ---------------------------------------------------------------------------
// MFMA flash attention, causal. BM=64, 1024 blocks, 4 blocks/CU.
// NEW: QK^T pipelined ONE K-TILE AHEAD. At step t: stage K(t+2)/V(t+1),
// softmax(t) + Ps write, QK(t+1) (its ds_reads+MFMAs fill the Ps
// write->read latency window), then Ps read + PV(t). K staged 2 ahead
// (prologue K0,V0,K1). Softmax denom via matrix pipe (P*ones -> osum).
// Buffer parity: K(t+1) in Ks[(t+1)&1], V(t) in Vs[t&1] - no races.
// ---------------------------------------------------------------------------
__global__ __launch_bounds__(256, 4) void attn_mfma(
    const unsigned short* __restrict__ Qb,   // [bh][s][64], pre-scaled 1/(8 ln2)
    const unsigned short* __restrict__ Kb,   // [bh][s][64]
    const unsigned short* __restrict__ Vt,   // [bh][64][S]
    unsigned short* __restrict__ Cb)         // [b][s][1024] bf16
{
    __shared__ unsigned short Ks[2][64][64];
    __shared__ unsigned short Vs[2][64][64];
    __shared__ unsigned short Ps[64][64];

    const int t    = threadIdx.x;
    const int lane = t & 63, wave = t >> 6;
    const int lm   = lane & 15, quad = lane >> 4;
    const int sw   = lm & 7;                 // 16B-chunk swizzle (K/V tiles)
    const int psw  = (lm & 7) << 1;          // 8B-chunk swizzle (Ps), even

    const int b     = blockIdx.x;
    const int bh    = b & 31;
    const int f     = (b >> 5) & 7;
    const int round = b >> 8;
    int qt;
    if      (round == 0) qt = f;
    else if (round == 1) qt = 15 - f;
    else if (round == 2) qt = 16 + f;
    else                 qt = 31 - f;
    const int q0 = qt * 64;

    const unsigned short* Qg = Qb + (size_t)bh * S * HD;
    const unsigned short* Kg = Kb + (size_t)bh * S * HD;
    const unsigned short* Vg = Vt + (size_t)bh * HD * S;

    short8 qa0 = *(const short8*)(Qg + (size_t)(q0 + 16 * wave + lm) * HD + quad * 8);
    short8 qa1 = *(const short8*)(Qg + (size_t)(q0 + 16 * wave + lm) * HD + 32 + quad * 8);

    short8 vones;
    #pragma unroll
    for (int i = 0; i < 8; ++i) vones[i] = (short)0x3F80;   // bf16 1.0

    // Prologue: stage K0 -> Ks[0], V0 -> Vs[0], K1 -> Ks[1]
    // (K1 is harmless garbage when qt == 0; never read.)
    #pragma unroll
    for (int i = 0; i < 2; ++i) {
        int c = t + i * 256;
        int row = c >> 3;
        int dkc = (c & 7) ^ (row & 7);
        GLD16(Kg + (size_t)row * HD + dkc * 8,        &Ks[0][0][0] + c * 8);
        GLD16(Vg + (size_t)row * S + dkc * 8,         &Vs[0][0][0] + c * 8);
        GLD16(Kg + (size_t)(64 + row) * HD + dkc * 8, &Ks[1][0][0] + c * 8);
    }

    floatx4 o[4] = {};
    floatx4 osum = {};
    floatx4 sc[4], scn[4];
    #pragma unroll
    for (int nt = 0; nt < 4; ++nt) scn[nt] = floatx4{0.f, 0.f, 0.f, 0.f};

    __syncthreads();

    // QK(0) from Ks[0]
    #pragma unroll
    for (int nt = 0; nt < 4; ++nt) {
        short8 kb0 = *(const short8*)&Ks[0][nt * 16 + lm][(quad ^ sw) * 8];
        short8 kb1 = *(const short8*)&Ks[0][nt * 16 + lm][((4 + quad) ^ sw) * 8];
        floatx4 s = {0.f, 0.f, 0.f, 0.f};
        s = MFMA16(kb0, qa0, s);   // SWAPPED: row=k, col=q
        s = MFMA16(kb1, qa1, s);
        sc[nt] = s;
    }

    for (int kt = 0; kt <= qt; ++kt) {
        const int pb = kt & 1;

        // stage K(t+2) -> Ks[pb] (overwrites K(t), last read at step t-1)
        if (kt + 2 <= qt) {
            const int k0n = (kt + 2) * 64;
            #pragma unroll
            for (int i = 0; i < 2; ++i) {
                int c = t + i * 256;
                int row = c >> 3;
                int dkc = (c & 7) ^ (row & 7);
                GLD16(Kg + (size_t)(k0n + row) * HD + dkc * 8, &Ks[pb][0][0] + c * 8);
            }
        }
        // stage V(t+1) -> Vs[pb^1] (overwrites V(t-1), read done)
        if (kt + 1 <= qt) {
            const int k0v = (kt + 1) * 64;
            #pragma unroll
            for (int i = 0; i < 2; ++i) {
                int c = t + i * 256;
                int row = c >> 3;
                int dkc = (c & 7) ^ (row & 7);
                GLD16(Vg + (size_t)row * S + k0v + dkc * 8, &Vs[pb ^ 1][0][0] + c * 8);
            }
        }

        // softmax on sc (tile kt)
        if (kt == qt) {
            #pragma unroll
            for (int nt = 0; nt < 4; ++nt)
                #pragma unroll
                for (int r = 0; r < 4; ++r) {
                    float pe = fexp2(sc[nt][r]);
                    if (nt * 16 + quad * 4 + r > 16 * wave + lm) pe = 0.0f;
                    sc[nt][r] = pe;
                }
        } else {
            #pragma unroll
            for (int nt = 0; nt < 4; ++nt)
                #pragma unroll
                for (int r = 0; r < 4; ++r)
                    sc[nt][r] = fexp2(sc[nt][r]);
        }

        // Ps write (packed bf16)
        #pragma unroll
        for (int nt = 0; nt < 4; ++nt) {
            uint2 pk;
            pk.x = pack2bf(sc[nt][0], sc[nt][1]);
            pk.y = pack2bf(sc[nt][2], sc[nt][3]);
            int cp = (nt * 4 + quad) ^ psw;
            *(uint2*)&Ps[16 * wave + lm][cp * 4] = pk;
        }

        // lookahead QK(t+1) from Ks[pb^1] - fills the Ps write->read window
        if (kt < qt) {
            #pragma unroll
            for (int nt = 0; nt < 4; ++nt) {
                short8 kb0 = *(const short8*)&Ks[pb ^ 1][nt * 16 + lm][(quad ^ sw) * 8];
                short8 kb1 = *(const short8*)&Ks[pb ^ 1][nt * 16 + lm][((4 + quad) ^ sw) * 8];
                floatx4 s = {0.f, 0.f, 0.f, 0.f};
                s = MFMA16(kb0, qa0, s);
                s = MFMA16(kb1, qa1, s);
                scn[nt] = s;
            }
        }

        // PV(t): Ps read (own-wave rows) + V frags from Vs[pb]
        short8 pa0 = *(const short8*)&Ps[16 * wave + lm][((quad * 2) ^ psw) * 4];
        short8 pa1 = *(const short8*)&Ps[16 * wave + lm][((8 + quad * 2) ^ psw) * 4];
        osum = MFMA16(pa0, vones, osum);   // row-sum of P via matrix pipe
        osum = MFMA16(pa1, vones, osum);
        #pragma unroll
        for (int nt = 0; nt < 4; ++nt) {
            short8 vb0 = *(const short8*)&Vs[pb][nt * 16 + lm][(quad ^ sw) * 8];
            short8 vb1 = *(const short8*)&Vs[pb][nt * 16 + lm][((4 + quad) ^ sw) * 8];
            o[nt] = MFMA16(pa0, vb0, o[nt]);
            o[nt] = MFMA16(pa1, vb1, o[nt]);
        }

        __syncthreads();

        #pragma unroll
        for (int nt = 0; nt < 4; ++nt) sc[nt] = scn[nt];
    }

    const int h = bh & (NH - 1), bb = bh >> 4;
    #pragma unroll
    for (int r = 0; r < 4; ++r) {
        float inv = 1.0f / osum[r];
        size_t row = (size_t)bb * S + q0 + 16 * wave + quad * 4 + r;
        #pragma unroll
        for (int nt = 0; nt < 4; ++nt)
            Cb[row * D + h * HD + nt * 16 + lm] = f2bf(o[nt][r] * inv);
    }
}

extern "C" void kernel_launch(void* const* d_in, const int* in_sizes, int n_in,
                              void* d_out, int out_size, void* d_ws, size_t ws_size,
                              hipStream_t stream) {
    (void)in_sizes; (void)n_in; (void)out_size; (void)ws_size;
    const float* x  = (const float*)d_in[0];
    const float* Wq = (const float*)d_in[1];
    const float* Wk = (const float*)d_in[2];
    const float* Wv = (const float*)d_in[3];
    const float* Wo = (const float*)d_in[4];
    float* out = (float*)d_out;

    char* w = (char*)d_ws;
    unsigned short* Qb  = (unsigned short*)(w);                              // 8 MB
    unsigned short* Kb  = (unsigned short*)(w + (((size_t)8)  << 20));       // 8 MB
    unsigned short* Vtb = (unsigned short*)(w + (((size_t)16) << 20));       // 8 MB
    unsigned short* Cb  = (unsigned short*)(w + (((size_t)24) << 20));       // 8 MB
    unsigned short* xb  = (unsigned short*)(w + (((size_t)32) << 20));       // 8 MB
    unsigned short* wqb = (unsigned short*)(w + (((size_t)40) << 20));       // 2 MB
    unsigned short* wkb = (unsigned short*)(w + (((size_t)42) << 20));
    unsigned short* wvb = (unsigned short*)(w + (((size_t)44) << 20));
    unsigned short* wob = (unsigned short*)(w + (((size_t)46) << 20));
    float2*         tab = (float2*)(w + (((size_t)48) << 20));               // 512 KB

    cvt_kernel<<<8256, 256, 0, stream>>>(x, Wq, Wk, Wv, Wo,
                                         xb, wqb, wkb, wvb, wob, tab);

    dim3 g1(NROWS / 128, 24);
    gemm_qkv_mfma<<<g1, 256, 0, stream>>>(xb, wqb, wkb, wvb, tab, Qb, Kb, Vtb);

    attn_mfma<<<1024, 256, 0, stream>>>(Qb, Kb, Vtb, Cb);

    dim3 g3(NROWS / 64, D / 128);
    gemm_out_mfma<<<g3, 256, 0, stream>>>(Cb, wob, out);
}

// Round 6
// 167.622 us; speedup vs baseline: 1.0544x; 1.0021x over previous
//
#include <hip/hip_runtime.h>
#include <math.h>

#define B  2
#define S  2048
#define D  1024
#define NH 16
#define HD 64
#define NROWS (B * S)   // 4096

#define AS1 __attribute__((address_space(1)))
#define AS3 __attribute__((address_space(3)))
#define GLD16(g, l) __builtin_amdgcn_global_load_lds((const AS1 void*)(g), (AS3 void*)(l), 16, 0, 0)

typedef __attribute__((ext_vector_type(8))) short short8;   // 8 bf16
typedef __attribute__((ext_vector_type(4))) float floatx4;

#define MFMA16(a, b, c) __builtin_amdgcn_mfma_f32_16x16x32_bf16((a), (b), (c), 0, 0, 0)

// raw v_exp_f32 (2^x); inputs bounded in this kernel -> no libm range fixup
__device__ inline float fexp2(float x) { return __builtin_amdgcn_exp2f(x); }

__device__ inline unsigned short f2bf(float f) {
    union { float f; unsigned int u; } v; v.f = f;
    unsigned int u = v.u;
    u += 0x7fffu + ((u >> 16) & 1);     // RNE
    return (unsigned short)(u >> 16);
}

// two f32 -> packed bf16x2 (round-half-up) in one v_perm_b32
__device__ inline unsigned int pack2bf(float a, float b) {
    unsigned int ua = __float_as_uint(a) + 0x8000u;
    unsigned int ub = __float_as_uint(b) + 0x8000u;
    return __builtin_amdgcn_perm(ub, ua, 0x07060302u);
}

// ---------------------------------------------------------------------------
// fp32 -> bf16 conversion for x + weights, and RoPE cos/sin table build.
// Table layout [j][s] float2 (j = even-dim/2, 0..31; s = 0..2047).
// ---------------------------------------------------------------------------
__global__ __launch_bounds__(256) void cvt_kernel(
    const float* __restrict__ x,  const float* __restrict__ Wq,
    const float* __restrict__ Wk, const float* __restrict__ Wv,
    const float* __restrict__ Wo,
    unsigned short* __restrict__ xb,  unsigned short* __restrict__ wqb,
    unsigned short* __restrict__ wkb, unsigned short* __restrict__ wvb,
    unsigned short* __restrict__ wob, float2* __restrict__ tab)
{
    size_t idx = (size_t)blockIdx.x * 256 + threadIdx.x;
    if (idx >= (2u << 20)) {                     // RoPE table region
        int tt = (int)(idx - (2u << 20));        // 0..16383
        int j  = tt >> 9;                        // 0..31
        int s0 = (tt & 511) << 2;                // 0..2044
        float invf = fexp2(-(float)j * (13.287712379549449f / 32.0f));
        #pragma unroll
        for (int p = 0; p < 4; ++p) {
            float sn, cs;
            __sincosf((float)(s0 + p) * invf, &sn, &cs);
            tab[j * 2048 + s0 + p] = make_float2(cs, sn);
        }
        return;
    }
    const float* src; unsigned short* dst; size_t off;
    if (idx < (1u << 20)) { src = x; dst = xb; off = idx << 2; }
    else {
        size_t r = idx - (1u << 20);
        int w = (int)(r >> 18);
        off = (r & ((1u << 18) - 1)) << 2;
        src = (w == 0) ? Wq : (w == 1) ? Wk : (w == 2) ? Wv : Wo;
        dst = (w == 0) ? wqb : (w == 1) ? wkb : (w == 2) ? wvb : wob;
    }
    float4 f = *(const float4*)(src + off);
    ushort4 o;
    o.x = f2bf(f.x); o.y = f2bf(f.y); o.z = f2bf(f.z); o.w = f2bf(f.w);
    *(ushort4*)(dst + off) = o;
}

// ---------------------------------------------------------------------------
// QKV GEMM: 128x128 tile, BK=32 double-buffered, 4 waves in 2x2, 4x4
// fragment acc. Grid (32,24)=768 blocks = 3/CU. 32 KB LDS.
// ---------------------------------------------------------------------------
#define G2STAGE(Abase, Bbase, kk, AD, BD)                                      \
{                                                                              \
    GLD16(Abase + (size_t)rowS        * D + (kk) + koS, AD + t * 8);           \
    GLD16(Abase + (size_t)(rowS + 64) * D + (kk) + koS, AD + 2048 + t * 8);    \
    GLD16(Bbase + (size_t)rowS        * D + (kk) + koS, BD + t * 8);           \
    GLD16(Bbase + (size_t)(rowS + 64) * D + (kk) + koS, BD + 2048 + t * 8);    \
}

#define G2COMP(AC, BC)                                                         \
{                                                                              \
    short8 a[4], b[4];                                                         \
    _Pragma("unroll")                                                          \
    for (int mi = 0; mi < 4; ++mi)                                             \
        a[mi] = *(const short8*)&AC[(wr * 64 + mi * 16 + lm) * 32 + quad * 8]; \
    _Pragma("unroll")                                                          \
    for (int ni = 0; ni < 4; ++ni)                                             \
        b[ni] = *(const short8*)&BC[(wc * 64 + ni * 16 + lm) * 32 + quad * 8]; \
    _Pragma("unroll")                                                          \
    for (int mi = 0; mi < 4; ++mi)                                             \
        _Pragma("unroll")                                                      \
        for (int ni = 0; ni < 4; ++ni)                                         \
            acc[mi][ni] = MFMA16(b[ni], a[mi], acc[mi][ni]);  /* SWAPPED */    \
}

__global__ __launch_bounds__(256, 3) void gemm_qkv_mfma(
    const unsigned short* __restrict__ xb,
    const unsigned short* __restrict__ wqb,
    const unsigned short* __restrict__ wkb,
    const unsigned short* __restrict__ wvb,
    const float2* __restrict__ tab,
    unsigned short* __restrict__ Qo, unsigned short* __restrict__ Ko,
    unsigned short* __restrict__ Vo)   // Vo = Vt [bh][64][S]
{
    __shared__ short As0[128 * 32];    // 8 KB each
    __shared__ short As1[128 * 32];
    __shared__ short Bs0[128 * 32];
    __shared__ short Bs1[128 * 32];    // total 32 KB

    const int t    = threadIdx.x;
    const int wave = t >> 6, lane = t & 63;
    const int lm   = lane & 15, quad = lane >> 4;
    const int wr   = wave >> 1, wc = wave & 1;
    const int rowS = t >> 2;
    const int koS  = (t & 3) << 3;

    const int i0  = blockIdx.x * 128;
    const int by  = blockIdx.y;                  // 0..23
    const int mat = by >> 3;                     // 0=Q 1=K 2=V
    const int j0  = (by & 7) * 128;
    const unsigned short* __restrict__ W = (mat == 0) ? wqb : (mat == 1) ? wkb : wvb;
    unsigned short* __restrict__ out = (mat == 0) ? Qo : (mat == 1) ? Ko : Vo;

    const unsigned short* Abase = xb + (size_t)i0 * D;
    const unsigned short* Bbase = W  + (size_t)j0 * D;

    floatx4 acc[4][4] = {};

    G2STAGE(Abase, Bbase, 0, As0, Bs0);
    __syncthreads();
    for (int k0 = 0; k0 < D; k0 += 64) {
        G2STAGE(Abase, Bbase, k0 + 32, As1, Bs1);
        G2COMP(As0, Bs0);
        __syncthreads();
        if (k0 + 64 < D) G2STAGE(Abase, Bbase, k0 + 64, As0, Bs0);
        G2COMP(As1, Bs1);
        __syncthreads();
    }

    const int h = (j0 + wc * 64) >> 6;           // head, constant per wave
    if (mat < 2) {
        // Q/K: RoPE via table (lane-local pairs), ushort4 stores [bh][s][hd]
        #pragma unroll
        for (int mi = 0; mi < 4; ++mi) {
            const int mg = i0 + wr * 64 + mi * 16 + lm;
            const int si = mg & (S - 1), bb = mg >> 11;
            unsigned short* orow = out + ((size_t)(bb * NH + h) * S + si) * HD;
            #pragma unroll
            for (int ni = 0; ni < 4; ++ni) {
                const int dim0 = ni * 16 + quad * 4;     // 0..63 within head
                const int j = dim0 >> 1;
                float2 t0 = tab[j * 2048 + si];
                float2 t1 = tab[(j + 1) * 2048 + si];
                floatx4 v = acc[mi][ni];
                float r0 = v[0] * t0.x - v[1] * t0.y;
                float r1 = v[0] * t0.y + v[1] * t0.x;
                float r2 = v[2] * t1.x - v[3] * t1.y;
                float r3 = v[2] * t1.y + v[3] * t1.x;
                if (mat == 0) {                  // fold 1/(8*ln2) into Q
                    r0 *= 0.1803368801111204f; r1 *= 0.1803368801111204f;
                    r2 *= 0.1803368801111204f; r3 *= 0.1803368801111204f;
                }
                ushort4 pk;
                pk.x = f2bf(r0); pk.y = f2bf(r1);
                pk.z = f2bf(r2); pk.w = f2bf(r3);
                *(ushort4*)(orow + dim0) = pk;
            }
        }
    } else {
        // V: store transposed into Vt[bh][d][s] (fused vtrans)
        #pragma unroll
        for (int mi = 0; mi < 4; ++mi) {
            const int mg = i0 + wr * 64 + mi * 16 + lm;
            const int si = mg & (S - 1), bb = mg >> 11;
            unsigned short* vb = out + (size_t)(bb * NH + h) * HD * S + si;
            #pragma unroll
            for (int ni = 0; ni < 4; ++ni) {
                const int d0 = ni * 16 + quad * 4;
                #pragma unroll
                for (int p = 0; p < 4; ++p)
                    vb[(size_t)(d0 + p) * S] = f2bf(acc[mi][ni][p]);
            }
        }
    }
}

// ---------------------------------------------------------------------------
// out-proj GEMM (unchanged 64x128 structure): out = Cb @ Wo^T, fp32 output.
// ---------------------------------------------------------------------------
#define GSTAGE(Abase, Bbase, kk, AD, BD)                                       \
{                                                                              \
    GLD16(Abase + (size_t)rowA  * D + (kk) + koA,  AD + cA  * 8);              \
    GLD16(Bbase + (size_t)rowB0 * D + (kk) + koB0, BD + cB0 * 8);              \
    GLD16(Bbase + (size_t)rowB1 * D + (kk) + koB1, BD + cB1 * 8);              \
}

#define GCOMP(AC, BC)                                                          \
{                                                                              \
    short8 a[4], b[2];                                                         \
    _Pragma("unroll")                                                          \
    for (int mi = 0; mi < 4; ++mi)                                             \
        a[mi] = *(const short8*)&AC[(mi * 16 + lm) * 32 + quad * 8];           \
    _Pragma("unroll")                                                          \
    for (int ni = 0; ni < 2; ++ni)                                             \
        b[ni] = *(const short8*)&BC[(wave * 32 + ni * 16 + lm) * 32 + quad * 8]; \
    _Pragma("unroll")                                                          \
    for (int mi = 0; mi < 4; ++mi)                                             \
        _Pragma("unroll")                                                      \
        for (int ni = 0; ni < 2; ++ni)                                         \
            acc[mi][ni] = MFMA16(b[ni], a[mi], acc[mi][ni]);  /* SWAPPED */    \
}

#define GEMM_PREAMBLE                                                          \
    const int t    = threadIdx.x;                                              \
    const int wave = t >> 6, lane = t & 63;                                    \
    const int lm   = lane & 15, quad = lane >> 4;                              \
    const int cA   = wave * 64 + lane;                                         \
    const int rowA = cA >> 2,  koA  = (cA & 3) << 3;                           \
    const int cB0  = wave * 128 + lane;                                        \
    const int rowB0 = cB0 >> 2, koB0 = (cB0 & 3) << 3;                         \
    const int cB1  = cB0 + 64;                                                 \
    const int rowB1 = cB1 >> 2, koB1 = (cB1 & 3) << 3;

#define GEMM_KLOOP(Abase, Bbase)                                               \
    GSTAGE(Abase, Bbase, 0, As0, Bs0);                                         \
    __syncthreads();                                                           \
    for (int k0 = 0; k0 < D; k0 += 64) {                                       \
        GSTAGE(Abase, Bbase, k0 + 32, As1, Bs1);                               \
        GCOMP(As0, Bs0);                                                       \
        __syncthreads();                                                       \
        if (k0 + 64 < D) GSTAGE(Abase, Bbase, k0 + 64, As0, Bs0);              \
        GCOMP(As1, Bs1);                                                       \
        __syncthreads();                                                       \
    }

__global__ __launch_bounds__(256) void gemm_out_mfma(
    const unsigned short* __restrict__ Cb,
    const unsigned short* __restrict__ wob,
    float* __restrict__ out)
{
    __shared__ short As0[64 * 32];
    __shared__ short As1[64 * 32];
    __shared__ short Bs0[128 * 32];
    __shared__ short Bs1[128 * 32];

    GEMM_PREAMBLE
    const int i0 = blockIdx.x * 64;
    const int j0 = blockIdx.y * 128;

    const unsigned short* Abase = Cb  + (size_t)i0 * D;
    const unsigned short* Bbase = wob + (size_t)j0 * D;

    floatx4 acc[4][2] = {};
    GEMM_KLOOP(Abase, Bbase)

    #pragma unroll
    for (int mi = 0; mi < 4; ++mi) {
        const int mg = i0 + mi * 16 + lm;
        float* orow = out + (size_t)mg * D;
        #pragma unroll
        for (int ni = 0; ni < 2; ++ni) {
            const int ng = j0 + wave * 32 + ni * 16 + quad * 4;
            *(floatx4*)(orow + ng) = acc[mi][ni];
        }
    }
}

// ---------------------------------------------------------------------------
// MFMA flash attention, causal. NEW: BM=128 with 8 WAVES (512 threads),
// each wave owns 16 q-rows (per-wave code identical to the proven R5 wave).
// K/V tile staged once per step is shared by 8 waves -> L2 staging traffic
// per MFMA halves vs BM=64. Grid 512 blocks = 2/CU = 16 waves/CU; block c
// (qt=c>>5) pairs with block c+256 (qt=15-c>>5) on the same CU -> every CU
// gets exactly 34 k-steps (perfect balance). Waves 0-3 skip the final
// k-tile (wave-uniform guard); waves 4-7 take the diagonal there.
// QK pipelined one tile ahead; softmax denom via matrix pipe (P*ones).
// LDS 48 KB: Ks[2]+Vs[2] 32 KB + Ps[128][64] 16 KB.
// ---------------------------------------------------------------------------
__global__ __launch_bounds__(512, 4) void attn_mfma(
    const unsigned short* __restrict__ Qb,   // [bh][s][64], pre-scaled 1/(8 ln2)
    const unsigned short* __restrict__ Kb,   // [bh][s][64]
    const unsigned short* __restrict__ Vt,   // [bh][64][S]
    unsigned short* __restrict__ Cb)         // [b][s][1024] bf16
{
    __shared__ unsigned short Ks[2][64][64];
    __shared__ unsigned short Vs[2][64][64];
    __shared__ unsigned short Ps[128][64];

    const int t    = threadIdx.x;            // 0..511
    const int lane = t & 63, wave = t >> 6;  // wave 0..7
    const int lm   = lane & 15, quad = lane >> 4;
    const int sw   = lm & 7;                 // 16B-chunk swizzle (K/V tiles)
    const int psw  = (lm & 7) << 1;          // 8B-chunk swizzle (Ps), even

    const int b     = blockIdx.x;            // 0..511
    const int bh    = b & 31;
    const int f     = (b >> 5) & 7;
    const int round = b >> 8;                // 0..1
    const int qt    = (round == 0) ? f : 15 - f;
    const int q0    = qt * 128;
    const int nkv   = 2 * qt + 2;            // block-level k-steps
    const int myNkv = 2 * qt + 1 + (wave >> 2);  // waves 0-3 skip last tile

    const unsigned short* Qg = Qb + (size_t)bh * S * HD;
    const unsigned short* Kg = Kb + (size_t)bh * S * HD;
    const unsigned short* Vg = Vt + (size_t)bh * HD * S;

    short8 qa0 = *(const short8*)(Qg + (size_t)(q0 + 16 * wave + lm) * HD + quad * 8);
    short8 qa1 = *(const short8*)(Qg + (size_t)(q0 + 16 * wave + lm) * HD + 32 + quad * 8);

    short8 vones;
    #pragma unroll
    for (int i = 0; i < 8; ++i) vones[i] = (short)0x3F80;   // bf16 1.0

    const int srow = t >> 3;                 // 0..63
    const int sch  = (t & 7) ^ (srow & 7);   // swizzled 16B chunk

    // Prologue: K0 -> Ks[0], V0 -> Vs[0], K1 -> Ks[1] (K1 valid rows even at qt=0)
    GLD16(Kg + (size_t)srow * HD + sch * 8,        &Ks[0][0][0] + t * 8);
    GLD16(Vg + (size_t)srow * S + sch * 8,         &Vs[0][0][0] + t * 8);
    GLD16(Kg + (size_t)(64 + srow) * HD + sch * 8, &Ks[1][0][0] + t * 8);

    floatx4 o[4] = {};
    floatx4 osum = {};
    floatx4 sc[4], scn[4];
    #pragma unroll
    for (int nt = 0; nt < 4; ++nt) scn[nt] = floatx4{0.f, 0.f, 0.f, 0.f};

    __syncthreads();

    // QK(0) from Ks[0]
    #pragma unroll
    for (int nt = 0; nt < 4; ++nt) {
        short8 kb0 = *(const short8*)&Ks[0][nt * 16 + lm][(quad ^ sw) * 8];
        short8 kb1 = *(const short8*)&Ks[0][nt * 16 + lm][((4 + quad) ^ sw) * 8];
        floatx4 s = {0.f, 0.f, 0.f, 0.f};
        s = MFMA16(kb0, qa0, s);   // SWAPPED: row=k, col=q
        s = MFMA16(kb1, qa1, s);
        sc[nt] = s;
    }

    __syncthreads();   // protect Ks[0] reads above from the kt=0 restage below

    for (int kt = 0; kt < nkv; ++kt) {
        const int pb = kt & 1;

        // stage K(t+2) -> Ks[pb] (overwrites K(t), reads finished at step t-1)
        if (kt + 2 < nkv)
            GLD16(Kg + (size_t)((kt + 2) * 64 + srow) * HD + sch * 8,
                  &Ks[pb][0][0] + t * 8);
        // stage V(t+1) -> Vs[pb^1] (overwrites V(t-1), reads finished)
        if (kt + 1 < nkv)
            GLD16(Vg + (size_t)srow * S + (kt + 1) * 64 + sch * 8,
                  &Vs[pb ^ 1][0][0] + t * 8);

        if (kt < myNkv) {                      // wave-uniform activity guard
            // softmax on sc (tile kt)
            if (kt == myNkv - 1) {
                const int rel = q0 + 16 * wave + lm - kt * 64;   // 0..63
                #pragma unroll
                for (int nt = 0; nt < 4; ++nt)
                    #pragma unroll
                    for (int r = 0; r < 4; ++r) {
                        float pe = fexp2(sc[nt][r]);
                        if (nt * 16 + quad * 4 + r > rel) pe = 0.0f;
                        sc[nt][r] = pe;
                    }
            } else {
                #pragma unroll
                for (int nt = 0; nt < 4; ++nt)
                    #pragma unroll
                    for (int r = 0; r < 4; ++r)
                        sc[nt][r] = fexp2(sc[nt][r]);
            }

            // Ps write (packed bf16), own-wave rows
            #pragma unroll
            for (int nt = 0; nt < 4; ++nt) {
                uint2 pk;
                pk.x = pack2bf(sc[nt][0], sc[nt][1]);
                pk.y = pack2bf(sc[nt][2], sc[nt][3]);
                int cp = (nt * 4 + quad) ^ psw;
                *(uint2*)&Ps[16 * wave + lm][cp * 4] = pk;
            }

            // lookahead QK(t+1) from Ks[pb^1] - fills Ps write->read window
            if (kt + 1 < myNkv) {
                #pragma unroll
                for (int nt = 0; nt < 4; ++nt) {
                    short8 kb0 = *(const short8*)&Ks[pb ^ 1][nt * 16 + lm][(quad ^ sw) * 8];
                    short8 kb1 = *(const short8*)&Ks[pb ^ 1][nt * 16 + lm][((4 + quad) ^ sw) * 8];
                    floatx4 s = {0.f, 0.f, 0.f, 0.f};
                    s = MFMA16(kb0, qa0, s);
                    s = MFMA16(kb1, qa1, s);
                    scn[nt] = s;
                }
            }

            // PV(t): Ps read (own-wave rows) + V frags from Vs[pb]
            short8 pa0 = *(const short8*)&Ps[16 * wave + lm][((quad * 2) ^ psw) * 4];
            short8 pa1 = *(const short8*)&Ps[16 * wave + lm][((8 + quad * 2) ^ psw) * 4];
            osum = MFMA16(pa0, vones, osum);   // row-sum of P via matrix pipe
            osum = MFMA16(pa1, vones, osum);
            #pragma unroll
            for (int nt = 0; nt < 4; ++nt) {
                short8 vb0 = *(const short8*)&Vs[pb][nt * 16 + lm][(quad ^ sw) * 8];
                short8 vb1 = *(const short8*)&Vs[pb][nt * 16 + lm][((4 + quad) ^ sw) * 8];
                o[nt] = MFMA16(pa0, vb0, o[nt]);
                o[nt] = MFMA16(pa1, vb1, o[nt]);
            }
        }

        __syncthreads();

        if (kt + 1 < myNkv) {
            #pragma unroll
            for (int nt = 0; nt < 4; ++nt) sc[nt] = scn[nt];
        }
    }

    const int h = bh & (NH - 1), bb = bh >> 4;
    #pragma unroll
    for (int r = 0; r < 4; ++r) {
        float inv = 1.0f / osum[r];
        size_t row = (size_t)bb * S + q0 + 16 * wave + quad * 4 + r;
        #pragma unroll
        for (int nt = 0; nt < 4; ++nt)
            Cb[row * D + h * HD + nt * 16 + lm] = f2bf(o[nt][r] * inv);
    }
}

extern "C" void kernel_launch(void* const* d_in, const int* in_sizes, int n_in,
                              void* d_out, int out_size, void* d_ws, size_t ws_size,
                              hipStream_t stream) {
    (void)in_sizes; (void)n_in; (void)out_size; (void)ws_size;
    const float* x  = (const float*)d_in[0];
    const float* Wq = (const float*)d_in[1];
    const float* Wk = (const float*)d_in[2];
    const float* Wv = (const float*)d_in[3];
    const float* Wo = (const float*)d_in[4];
    float* out = (float*)d_out;

    char* w = (char*)d_ws;
    unsigned short* Qb  = (unsigned short*)(w);                              // 8 MB
    unsigned short* Kb  = (unsigned short*)(w + (((size_t)8)  << 20));       // 8 MB
    unsigned short* Vtb = (unsigned short*)(w + (((size_t)16) << 20));       // 8 MB
    unsigned short* Cb  = (unsigned short*)(w + (((size_t)24) << 20));       // 8 MB
    unsigned short* xb  = (unsigned short*)(w + (((size_t)32) << 20));       // 8 MB
    unsigned short* wqb = (unsigned short*)(w + (((size_t)40) << 20));       // 2 MB
    unsigned short* wkb = (unsigned short*)(w + (((size_t)42) << 20));
    unsigned short* wvb = (unsigned short*)(w + (((size_t)44) << 20));
    unsigned short* wob = (unsigned short*)(w + (((size_t)46) << 20));
    float2*         tab = (float2*)(w + (((size_t)48) << 20));               // 512 KB

    cvt_kernel<<<8256, 256, 0, stream>>>(x, Wq, Wk, Wv, Wo,
                                         xb, wqb, wkb, wvb, wob, tab);

    dim3 g1(NROWS / 128, 24);
    gemm_qkv_mfma<<<g1, 256, 0, stream>>>(xb, wqb, wkb, wvb, tab, Qb, Kb, Vtb);

    attn_mfma<<<512, 512, 0, stream>>>(Qb, Kb, Vtb, Cb);

    dim3 g3(NROWS / 64, D / 128);
    gemm_out_mfma<<<g3, 256, 0, stream>>>(Cb, wob, out);
}